// Round 6
// baseline (246.602 us; speedup 1.0000x reference)
//
#include <hip/hip_runtime.h>
#include <stdint.h>

// WindowWarp: B=256, T=2048, C=64, WINDOW_RATIO=0.1, SCALES={0.5,2.0}
// WARP_SIZE = ceil(0.1*2048) = 205
// L_MAX = T - WARP_SIZE + int(WARP_SIZE*2.0) = 1843 + 410 = 2253
constexpr int Bn     = 256;
constexpr int Tn     = 2048;
constexpr int Cn     = 64;
constexpr int WARPSZ = 205;
constexpr int LMAX   = 2253;

constexpr int TB     = 32;   // t-rows per tile
constexpr int NR     = 80;   // staged source rows per tile (worst-case span ~66;
                             // padded to 80 so chunks=20 -> 5 per wave, uniform vmcnt)
constexpr int NTILES = 8;    // tiles per block -> 256 t-rows per block
// LDS: 2 buffers * 80 rows * 256 B = 40960 B -> 4 blocks/CU.

typedef float f32x4 __attribute__((ext_vector_type(4)));

// Map intermediate index j -> source position s -> (i0, i1, frac) into x rows.
// Arithmetic byte-identical to the passing round-3/4 kernels.
// NOTE: with integer start/nl, s is monotone nondecreasing in integer j, so the
// block-uniform r0a computed at the tile's first j is the true minimum row.
__device__ __forceinline__ void map_j(float jf, float start, float nl, float rdenom,
                                      int& i0, int& i1, float& fr) {
    bool in_win = (jf >= start) && (jf < start + nl);
    bool after  = (jf >= start + nl);
    float s_win   = start + (jf - start) * rdenom;      // rdenom = (WARP-1)/max(nl-1,1)
    float s_after = jf - nl + (float)WARPSZ;
    float s = in_win ? s_win : (after ? s_after : jf);
    s = fminf(fmaxf(s, 0.0f), (float)(Tn - 1));
    float p0 = floorf(s);
    fr = s - p0;
    i0 = (int)p0;
    i1 = min(i0 + 1, Tn - 1);
}

__global__ __launch_bounds__(256) void window_warp_kernel(
        const float* __restrict__ x,
        const float* __restrict__ scales,
        const int*   __restrict__ starts,
        float*       __restrict__ out) {
    __shared__ f32x4 smem[2][NR * (Cn / 4)];   // 2 x 20 KB

    // 2048 blocks = 8 XCDs * 256. Bijective swizzle: consecutive logical blocks
    // (same batch, overlapping staged rows) land on the same XCD's L2.
    int n       = blockIdx.x;
    int logical = ((n & 7) << 8) | (n >> 3);
    int b        = logical >> 3;            // 8 blocks per batch (wave-uniform)
    int t_origin = (logical & 7) << 8;      // 256 consecutive t-rows per block
    int tslot = threadIdx.x >> 4;           // 0..15
    int cg    = threadIdx.x & 15;
    int wave  = threadIdx.x >> 6;           // 0..3
    int lane  = threadIdx.x & 63;

    float scale = scales[b];
    float start = (float)starts[b];
    float nl    = floorf((float)WARPSZ * scale);        // new_len
    float Lm1   = (float)(Tn - WARPSZ) + nl - 1.0f;     // L - 1
    float rdenom = (float)(WARPSZ - 1) / fmaxf(nl - 1.0f, 1.0f);

    const float* xb   = x + (size_t)b * (Tn * Cn);
    f32x4*       outb = (f32x4*)(out + (size_t)b * (Tn * Cn));

    // Per-tile first source row (block-uniform; map is monotone in t and j).
    int rb[NTILES];
    #pragma unroll
    for (int tau = 0; tau < NTILES; ++tau) {
        int t0 = t_origin + tau * TB;
        float u0 = ((float)t0 * Lm1) / (float)(Tn - 1);
        u0 = fminf(fmaxf(u0, 0.0f), Lm1);
        int j00 = (int)floorf(u0);
        int ra, rx; float fr;
        map_j((float)j00, start, nl, rdenom, ra, rx, fr);
        rb[tau] = min(ra, Tn - NR);         // rows [rb, rb+NR) stay in-range
    }

    // Issue 20 x 1KB global_load_lds for one tile: 5 per wave (uniform so the
    // counted vmcnt below is the same literal in every wave).
    auto STAGE = [&](int bufidx, int rbase) {
        const float* gb = xb + rbase * Cn;
        float* sm = (float*)&smem[bufidx][0];
        #pragma unroll
        for (int j = 0; j < 5; ++j) {
            int c = wave + 4 * j;
            __builtin_amdgcn_global_load_lds(
                (const __attribute__((address_space(1))) uint32_t*)(gb + c * 256 + lane * 4),
                (__attribute__((address_space(3))) uint32_t*)(sm + c * 256),
                16, 0, 0);
        }
    };

    auto COMPUTE = [&](int bufidx, int t0, int rbase) {
        int   i00[2], i01[2], i10[2], i11[2];
        float f0[2], f1[2], fu[2];
        #pragma unroll
        for (int k = 0; k < 2; ++k) {
            int t = t0 + tslot + 16 * k;
            float u = ((float)t * Lm1) / (float)(Tn - 1);
            u = fminf(fmaxf(u, 0.0f), Lm1);
            float q0 = floorf(u);
            fu[k] = u - q0;
            int j0 = (int)q0;
            int j1 = min(j0 + 1, LMAX - 1);
            map_j((float)j0, start, nl, rdenom, i00[k], i01[k], f0[k]);
            map_j((float)j1, start, nl, rdenom, i10[k], i11[k], f1[k]);
        }
        const f32x4* sm = &smem[bufidx][0];
        f32x4 A0[2], A1[2], B0[2], B1[2];
        #pragma unroll
        for (int k = 0; k < 2; ++k) {
            A0[k] = sm[(i00[k] - rbase) * 16 + cg];
            A1[k] = sm[(i01[k] - rbase) * 16 + cg];
            B0[k] = sm[(i10[k] - rbase) * 16 + cg];
            B1[k] = sm[(i11[k] - rbase) * 16 + cg];
        }
        #pragma unroll
        for (int k = 0; k < 2; ++k) {
            int t = t0 + tslot + 16 * k;
            float g0 = 1.0f - f0[k], g1 = 1.0f - f1[k], gu = 1.0f - fu[k];
            f32x4 v0 = A0[k] * g0 + A1[k] * f0[k];
            f32x4 v1 = B0[k] * g1 + B1[k] * f1[k];
            f32x4 r  = v0 * gu + v1 * fu[k];
            __builtin_nontemporal_store(r, (f32x4*)&outb[t * 16 + cg]);
        }
    };

    // --- Software-pipelined tile loop. Counted vmcnt (never 0 mid-loop):
    // per-wave outstanding at the wait, oldest-first:
    //   tau==0      : [loads_0 x5][loads_1 x5]                 -> vmcnt(5)
    //   0<tau<NT-1  : [loads_t x5][stores x2][loads_{t+1} x5]  -> vmcnt(7)
    //   tau==NT-1   : [loads_t x5][stores x2]                  -> vmcnt(2)
    // Raw s_barrier (NOT __syncthreads) so the compiler doesn't re-insert a
    // vmcnt(0) drain; barrier after the wait publishes all waves' LDS data.
    STAGE(0, rb[0]);
    #pragma unroll
    for (int tau = 0; tau < NTILES; ++tau) {
        if (tau >= 1)
            __builtin_amdgcn_s_barrier();       // readers of buf[(tau+1)&1] done
        if (tau + 1 < NTILES)
            STAGE((tau + 1) & 1, rb[tau + 1]);  // prefetch next tile
        if (tau == 0)
            asm volatile("s_waitcnt vmcnt(5)" ::: "memory");
        else if (tau + 1 < NTILES)
            asm volatile("s_waitcnt vmcnt(7)" ::: "memory");
        else
            asm volatile("s_waitcnt vmcnt(2)" ::: "memory");
        __builtin_amdgcn_s_barrier();           // tile tau fully in LDS
        COMPUTE(tau & 1, t_origin + tau * TB, rb[tau]);
    }
}

extern "C" void kernel_launch(void* const* d_in, const int* in_sizes, int n_in,
                              void* d_out, int out_size, void* d_ws, size_t ws_size,
                              hipStream_t stream) {
    const float* x      = (const float*)d_in[0];
    const float* scales = (const float*)d_in[1];
    const int*   starts = (const int*)d_in[2];
    float* out = (float*)d_out;

    // B*T rows / (32 rows * 8 tiles) = 2048 blocks (= 8 XCDs * 256).
    int blocks = Bn * Tn / (TB * NTILES);
    window_warp_kernel<<<blocks, 256, 0, stream>>>(x, scales, starts, out);
}